// Round 5
// baseline (435.629 us; speedup 1.0000x reference)
//
#include <hip/hip_runtime.h>
#include <stdint.h>

typedef _Float16 f16_t;
typedef _Float16 f16x4 __attribute__((ext_vector_type(4)));
typedef _Float16 f16x8 __attribute__((ext_vector_type(8)));
typedef float f32x4 __attribute__((ext_vector_type(4)));

// ---------------------------------------------------------------------------
// async global->LDS, 16B per lane. LDS dest is wave-uniform base + lane*16.
// ---------------------------------------------------------------------------
__device__ __forceinline__ void async16(const void* g, void* lds) {
    typedef __attribute__((address_space(3))) void lds_void;
    typedef __attribute__((address_space(1))) void glb_void;
    lds_void* l = (lds_void*)(unsigned int)(unsigned long long)lds;
    glb_void* gp = (glb_void*)(unsigned long long)g;
    __builtin_amdgcn_global_load_lds(gp, l, 16, 0, 0);
}

// ---------------------------------------------------------------------------
// gemm_core:  C[m,n] = sum_k A[m,k] * Bt[n,k]
// BK=32, 16x16x32 f16 MFMA, 256 threads = 4 waves (WM x WN), TM x TN per wave.
// Double-buffered LDS, one barrier per K-step; prefetch issued before compute.
//
// FA=0: A f16 [M][K] (ldA), staged via global_load_lds.
// FA=1: A fp32 [M][K] (ldA): float4 loads -> reg cvt f16 -> ds_write (same
//       [m][BK] LDS layout as FA=0). Fuses the weight cvt into the GEMM.
// FB=0: B f16 [N][K] (ldB=Kfull), staged via global_load_lds.
// FB=1: B fp32 [K][N] NATURAL layout (ldB = row stride): float4 loads -> cvt
//       -> ds_write into [BK][BN] with XOR swizzle hw = k*BN + (n ^ 8*((k>>3)&3));
//       fragment read = 8x ds_read_u16 at hw = k*BN + (n ^ 8*l4).
//       Fuses the input transpose+cvt into the GEMM (no HBM round-trip).
//
// MODE 0: f16 C.   MODE 1: fp32 C (C pre-offset by wrapper; used for split-K
// slabs too).   MODE 2: f16 gamma*acc + resid.   MODE 3: f16 C + f16 C^T
// dual-write (LDS-staged transpose aliasing the staging pool).
// ---------------------------------------------------------------------------
template <int BM, int BN, int TM, int TN, int WM, int WN, int MODE, int FA, int FB>
__device__ __forceinline__ void gemm_core(
    const void* __restrict__ Aop,      // pre-offset to tile rows (row0b)
    const void* __restrict__ Bop,      // FB=0: pre-offset to tile rows (col0b); FB=1: +col0b
    void* __restrict__ C,              // batch (or slab) base, row stride ldC
    const f16_t* __restrict__ resid,
    const float* __restrict__ gamma,
    f16_t* __restrict__ Ct,            // batch base, row stride ldCt
    int ldC, int ldCt, int ldA, int ldB,
    int kBeg, int kEnd, int row0b, int col0b,
    f16_t* __restrict__ pool) {
    constexpr int BK = 32;
    constexpr int ASZ = BM * BK;
    constexpr int BSZ = BN * BK;
    static_assert(FB == 0 || BN == 128, "fused-B path assumes BN=128");

    const int tid = threadIdx.x;
    const int wave = tid >> 6;
    const int lane = tid & 63;
    const int wm = wave / WN;
    const int wn = wave % WN;
    const int l16 = lane & 15;
    const int l4 = lane >> 4;

    const f16_t* A16 = (const f16_t*)Aop;
    const float* A32 = (const float*)Aop;
    const f16_t* B16 = (const f16_t*)Bop;
    const float* B32 = (const float*)Bop;

    f32x4 zero = {0.f, 0.f, 0.f, 0.f};
    f32x4 acc[TM][TN];
#pragma unroll
    for (int i = 0; i < TM; ++i)
#pragma unroll
        for (int j = 0; j < TN; ++j) acc[i][j] = zero;

    // ---- A staging ---------------------------------------------------------
    float4 ar[FA ? 4 : 1];
    auto loadA = [&](int k0) {
        if (FA) {
#pragma unroll
            for (int s = 0; s < 4; ++s) {
                int seg = s * 256 + tid;                 // BM*BK/4 = 1024 segs
                ar[s] = *(const float4*)(A32 + (long long)(seg >> 3) * ldA + k0 + (seg & 7) * 4);
            }
        }
    };
    auto writeA = [&](int b) {
        if (FA) {
            f16_t* As = pool + b * ASZ;
#pragma unroll
            for (int s = 0; s < 4; ++s) {
                int seg = s * 256 + tid;
                f16x4 h;
                h[0] = (f16_t)ar[s].x; h[1] = (f16_t)ar[s].y;
                h[2] = (f16_t)ar[s].z; h[3] = (f16_t)ar[s].w;
                *(f16x4*)&As[(seg >> 3) * BK + (seg & 7) * 4] = h;
            }
        }
    };
    auto stageA = [&](int b, int k0) {
        f16_t* As = pool + b * ASZ;
#pragma unroll
        for (int r = 0; r < (BM * 4) / 256; ++r) {
            int seg = r * 256 + tid;
            const f16_t* g = A16 + (long long)(seg >> 2) * ldA + k0 + (seg & 3) * 8;
            async16(g, &As[(r * 256 + wave * 64) * 8]);
        }
    };
    // ---- B staging ---------------------------------------------------------
    float4 br[FB ? 4 : 1];
    const int fk = tid >> 3;
    const int fc = (tid & 7) * 4;
    const int fswz = ((fk >> 3) & 3) * 8;
    auto loadB = [&](int k0) {
        if (FB) {
#pragma unroll
            for (int i = 0; i < 4; ++i)
                br[i] = *(const float4*)(B32 + (long long)(k0 + fk) * ldB + fc + i * 32);
        }
    };
    auto writeB = [&](int b) {
        if (FB) {
            f16_t* Bs = pool + 2 * ASZ + b * BSZ;
#pragma unroll
            for (int i = 0; i < 4; ++i) {
                int n4 = fc + i * 32;
                f16x4 h;
                h[0] = (f16_t)br[i].x; h[1] = (f16_t)br[i].y;
                h[2] = (f16_t)br[i].z; h[3] = (f16_t)br[i].w;
                *(f16x4*)&Bs[fk * BN + (n4 ^ fswz)] = h;
            }
        }
    };
    auto stageB = [&](int b, int k0) {
#pragma unroll
        for (int r = 0; r < (BN * 4) / 256; ++r) {
            int seg = r * 256 + tid;
            const f16_t* g = B16 + (long long)(seg >> 2) * ldB + k0 + (seg & 3) * 8;
            async16(g, &pool[2 * ASZ + b * BSZ + (r * 256 + wave * 64) * 8]);
        }
    };

    // ---- compute one K-step ------------------------------------------------
    auto compute = [&](int b) {
        const f16_t* As = pool + b * ASZ;
        const f16_t* Bs = pool + 2 * ASZ + b * BSZ;
        f16x8 af[TM], bfr[TN];
#pragma unroll
        for (int i = 0; i < TM; ++i)
            af[i] = *(const f16x8*)&As[((wm * TM + i) * 16 + l16) * BK + l4 * 8];
        if (FB) {
#pragma unroll
            for (int j = 0; j < TN; ++j) {
                const int nj = ((wn * TN + j) * 16 + l16) ^ (l4 * 8);
                f16x8 t;
#pragma unroll
                for (int e = 0; e < 8; ++e)
                    t[e] = Bs[(l4 * 8 + e) * BN + nj];
                bfr[j] = t;
            }
        } else {
#pragma unroll
            for (int j = 0; j < TN; ++j)
                bfr[j] = *(const f16x8*)&Bs[((wn * TN + j) * 16 + l16) * BK + l4 * 8];
        }
#pragma unroll
        for (int i = 0; i < TM; ++i)
#pragma unroll
            for (int j = 0; j < TN; ++j)
                acc[i][j] = __builtin_amdgcn_mfma_f32_16x16x32_f16(af[i], bfr[j], acc[i][j], 0, 0, 0);
    };

    // ---- main loop ---------------------------------------------------------
    const int NT = (kEnd - kBeg) / BK;
    int cur = 0;
    if (FA) loadA(kBeg); else stageA(0, kBeg);
    if (FB) loadB(kBeg); else stageB(0, kBeg);
    writeA(0);
    writeB(0);
    __syncthreads();
    for (int t = 1; t < NT; ++t) {
        const int k0 = kBeg + t * BK;
        if (FA) loadA(k0); else stageA(cur ^ 1, k0);
        if (FB) loadB(k0); else stageB(cur ^ 1, k0);
        compute(cur);
        writeA(cur ^ 1);
        writeB(cur ^ 1);
        __syncthreads();
        cur ^= 1;
    }
    compute(cur);

    if (MODE == 3) __syncthreads();      // Lt aliases staging pool

    // ---- epilogue: C/D layout col = lane&15, row = (lane>>4)*4 + reg -------
    const int row0 = row0b + wm * TM * 16;
    const int col0 = col0b + wn * TN * 16;
    const float g = (MODE == 2) ? gamma[0] : 0.f;
#pragma unroll
    for (int i = 0; i < TM; ++i) {
#pragma unroll
        for (int j = 0; j < TN; ++j) {
            f16x4 tq;
#pragma unroll
            for (int r = 0; r < 4; ++r) {
                int row = row0 + i * 16 + l4 * 4 + r;
                int col = col0 + j * 16 + l16;
                long long idx = (long long)row * ldC + col;
                float v = acc[i][j][r];
                if (MODE == 0) {
                    ((f16_t*)C)[idx] = (f16_t)v;
                } else if (MODE == 1) {
                    ((float*)C)[idx] = v;
                } else if (MODE == 2) {
                    float im = (float)resid[idx];
                    ((f16_t*)C)[idx] = (f16_t)(g * v + im);
                } else if (MODE == 3) {
                    ((f16_t*)C)[idx] = (f16_t)v;
                    tq[r] = (f16_t)v;
                }
            }
            if (MODE == 3) {
                int rl = wm * (TM * 16) + i * 16 + l4 * 4;
                int cl = wn * (TN * 16) + j * 16 + l16;
                *(f16x4*)&pool[cl * (BM + 8) + rl] = tq;
            }
        }
    }

    if (MODE == 3) {
        __syncthreads();
        constexpr int TPR = BM / 8;        // threads per transposed row
        constexpr int RPI = 256 / TPR;     // rows per iteration
#pragma unroll
        for (int it = 0; it < BN / RPI; ++it) {
            int nl = it * RPI + (tid / TPR);
            int c8 = (tid % TPR) * 8;
            f16x8 v = *(const f16x8*)&pool[nl * (BM + 8) + c8];
            *(f16x8*)&Ct[(long long)(col0b + nl) * ldCt + row0b + c8] = v;
        }
    }
}

// ---------------------------------------------------------------------------
// G12: merged projections. z<16: img/imgT = w_img x x1[b]; else kv/kvT from x2.
// fp32 weights (FA) and fp32 natural-layout activations (FB) consumed directly.
// ---------------------------------------------------------------------------
__global__ __launch_bounds__(256, 3) void g12(
    const float* __restrict__ x1, const float* __restrict__ x2,
    const float* __restrict__ w_img, const float* __restrict__ w_txt,
    f16_t* __restrict__ img, f16_t* __restrict__ imgT,
    f16_t* __restrict__ kv, f16_t* __restrict__ kvT) {
    __shared__ __align__(16) f16_t pool[128 * (128 + 8)];   // 34816 B
    const int z = blockIdx.z;
    const bool is1 = z < 16;
    const int b = is1 ? z : z - 16;
    const int K = is1 ? 512 : 320;
    const float* A = is1 ? w_img : w_txt;
    const float* Bf = (is1 ? x1 : x2) + (long long)b * K * 4096;
    f16_t* C = (is1 ? img : kv) + (long long)b * (256LL * 4096);
    f16_t* Ct = (is1 ? imgT : kvT) + (long long)b * (4096LL * 256);
    const int row0 = blockIdx.y * 128;
    const int col0 = blockIdx.x * 128;
    gemm_core<128, 128, 4, 4, 2, 2, 3, 1, 1>(
        A + (long long)row0 * K, Bf + col0,
        C, nullptr, nullptr, Ct,
        4096, 256, K, 4096, 0, K, row0, col0, pool);
}

// ---------------------------------------------------------------------------
// G3: attn partial slabs.  z = b*16+ks; slab = img[b] x kv[b]^T over K-slice.
// ---------------------------------------------------------------------------
__global__ __launch_bounds__(256, 3) void g3(
    const f16_t* __restrict__ img, const f16_t* __restrict__ kv,
    float* __restrict__ part) {
    __shared__ __align__(16) f16_t pool[4 * 128 * 32];      // 32 KB
    const int z = blockIdx.z;
    const int b = z >> 4, ks = z & 15;
    const int row0 = blockIdx.y * 128;
    const int col0 = blockIdx.x * 128;
    const long long NC = 256LL * 4096;
    gemm_core<128, 128, 4, 4, 2, 2, 1, 0, 0>(
        img + b * NC + (long long)row0 * 4096,
        kv + b * NC + (long long)col0 * 4096,
        part + (long long)z * 65536, nullptr, nullptr, nullptr,
        256, 0, 4096, 4096, ks * 256, ks * 256 + 256, row0, col0, pool);
}

// ---------------------------------------------------------------------------
// G4: yT = gamma*(kvT x attns^T) + imgT   [N,C] f16
// ---------------------------------------------------------------------------
__global__ __launch_bounds__(256, 3) void g4(
    const f16_t* __restrict__ kvT, const f16_t* __restrict__ attns,
    const f16_t* __restrict__ imgT, const float* __restrict__ gamma,
    f16_t* __restrict__ yT) {
    __shared__ __align__(16) f16_t pool[4 * 128 * 32];
    const int b = blockIdx.z;
    const int row0 = blockIdx.y * 128;                      // over N=4096
    const int col0 = blockIdx.x * 128;                      // over C=256
    const long long NC = 4096LL * 256;
    gemm_core<128, 128, 4, 4, 2, 2, 2, 0, 0>(
        kvT + b * NC + (long long)row0 * 256,
        attns + b * 65536LL + (long long)col0 * 256,
        yT + b * NC, imgT + b * NC, gamma, nullptr,
        256, 0, 256, 256, 0, 256, row0, col0, pool);
}

// ---------------------------------------------------------------------------
// G5: out = w_out x yT^T   [OC,N] fp32  (fp32 weights via FA)
// ---------------------------------------------------------------------------
__global__ __launch_bounds__(256, 3) void g5(
    const float* __restrict__ w_out, const f16_t* __restrict__ yT,
    float* __restrict__ out) {
    __shared__ __align__(16) f16_t pool[4 * 128 * 32];
    const int b = blockIdx.z;
    const int row0 = blockIdx.y * 128;                      // over OC=512
    const int col0 = blockIdx.x * 128;                      // over N=4096
    gemm_core<128, 128, 4, 4, 2, 2, 1, 1, 0>(
        w_out + (long long)row0 * 256,
        yT + b * (4096LL * 256) + (long long)col0 * 256,
        out + b * (512LL * 4096), nullptr, nullptr, nullptr,
        4096, 0, 256, 256, 0, 256, row0, col0, pool);
}

// ---------------------------------------------------------------------------
// fused split-K reduce + softmax over rows of 256 -> fp16.
// Partials: [B][KS][256][256] fp32.  One wave per row, 4 rows per block.
// ---------------------------------------------------------------------------
template <int KS>
__global__ void softmax_red(const float* __restrict__ part, f16_t* __restrict__ out) {
    const int row = blockIdx.x * 4 + (threadIdx.x >> 6);   // [0, B*256)
    const int lane = threadIdx.x & 63;
    const int b = row >> 8, r = row & 255;
    const float* p = part + (long long)(b * KS) * 65536 + r * 256 + lane * 4;
    float4 v = *(const float4*)p;
#pragma unroll
    for (int k = 1; k < KS; ++k) {
        float4 u = *(const float4*)(p + (long long)k * 65536);
        v.x += u.x; v.y += u.y; v.z += u.z; v.w += u.w;
    }
    float m = fmaxf(fmaxf(v.x, v.y), fmaxf(v.z, v.w));
#pragma unroll
    for (int off = 32; off > 0; off >>= 1) m = fmaxf(m, __shfl_xor(m, off, 64));
    float e0 = __expf(v.x - m), e1 = __expf(v.y - m);
    float e2 = __expf(v.z - m), e3 = __expf(v.w - m);
    float s = e0 + e1 + e2 + e3;
#pragma unroll
    for (int off = 32; off > 0; off >>= 1) s += __shfl_xor(s, off, 64);
    const float inv = 1.0f / s;
    f16x4 o;
    o[0] = (f16_t)(e0 * inv);
    o[1] = (f16_t)(e1 * inv);
    o[2] = (f16_t)(e2 * inv);
    o[3] = (f16_t)(e3 * inv);
    *(f16x4*)(out + ((long long)row) * 256 + lane * 4) = o;
}

// ---------------------------------------------------------------------------
// Orchestration — 5 launches, no standalone transposes/cvt:
//   G12: img+imgT and kv+kvT from fp32 x1/x2/weights (merged, fused cvt+T)
//   G3 : partial[b][ks][C][C] fp32  (128^2 tiles, split-K=16, plain stores)
//   SM : attns = softmax(sum_ks partial) f16
//   G4 : yT = gamma*(kvT x attns^T) + imgT  [N,C]
//   G5 : out = w_out x yT^T  [OC,N] fp32 (fused weight cvt)
// ---------------------------------------------------------------------------
extern "C" void kernel_launch(void* const* d_in, const int* in_sizes, int n_in,
                              void* d_out, int out_size, void* d_ws, size_t ws_size,
                              hipStream_t stream) {
    (void)in_sizes; (void)n_in; (void)out_size; (void)ws_size;

    const float* x1 = (const float*)d_in[0];     // [16,512,64,64]
    const float* x2 = (const float*)d_in[1];     // [16,320,64,64]
    const float* w_img = (const float*)d_in[2];  // [256,512]
    const float* w_txt = (const float*)d_in[3];  // [256,320]
    const float* w_out = (const float*)d_in[4];  // [512,256]
    const float* gamma = (const float*)d_in[5];  // [1]

    // ws layout (bytes): peak 102,760,448 (~98 MiB)
    char* ws = (char*)d_ws;
    f16_t* img   = (f16_t*)(ws + 0);           // 33554432
    f16_t* imgT  = (f16_t*)(ws + 33554432);    // 33554432
    f16_t* kvT   = (f16_t*)(ws + 67108864);    // 33554432
    f16_t* attns = (f16_t*)(ws + 100663296);   // 2097152 -> 102760448
    f16_t* yT    = img;                        // img dead after G3

    // d_out as scratch; G5 overwrites all of it (134217728 B)
    char* oc = (char*)d_out;
    f16_t* kv   = (f16_t*)oc;                  // [0, 33554432)
    float* part = (float*)(oc + 33554432);     // 16*16*65536*4 = 67108864 -> 100663296

    // 1. G12: both projections, dual-write, fused transpose+cvt
    g12<<<dim3(32, 2, 32), 256, 0, stream>>>(x1, x2, w_img, w_txt, img, imgT, kv, kvT);

    // 2. G3: attn partial slabs (M=N=256, K=4096, split-K=16)
    g3<<<dim3(2, 2, 256), 256, 0, stream>>>(img, kv, part);

    // 3. fused reduce + softmax -> f16
    softmax_red<16><<<1024, 256, 0, stream>>>(part, attns);

    // 4. G4: yT = gamma*(kvT x attns^T) + imgT   (M=4096, N=256, K=256)
    g4<<<dim3(2, 32, 16), 256, 0, stream>>>(kvT, attns, imgT, gamma, yT);

    // 5. G5: out = w_out x yT^T   (M=512, N=4096, K=256)
    g5<<<dim3(32, 4, 16), 256, 0, stream>>>(w_out, yT, (float*)d_out);
}